// Round 7
// baseline (216.441 us; speedup 1.0000x reference)
//
#include <hip/hip_runtime.h>

#define N_NODES 100000
#define E_EDGES 1600000

// bucketed CSR build
#define BSHIFT 7
#define BSIZE 128
#define NBUCK ((N_NODES + BSIZE - 1) / BSIZE)           // 782
#define STAGE_TPB 512
#define STAGE_EPT 8
#define STAGE_CHUNK (STAGE_TPB * STAGE_EPT)             // 4096
#define NSTAGE ((E_EDGES + STAGE_CHUNK - 1) / STAGE_CHUNK)  // 391
#define NGEMM 121                                        // fused GEMM blocks (grid = 512 total)
#define NREP 2                                           // LDS histogram replicas in stage
#define BUCKET_CAP 4096                                  // staged slots per bucket (mean 2046)
#define CSR_STRIDE (BUCKET_CAP + 512)                    // fixed csrc ints per bucket (4-aligned)

typedef __attribute__((ext_vector_type(8))) short short8;
typedef __attribute__((ext_vector_type(4))) float float4v;
typedef __attribute__((ext_vector_type(2))) float float2v;
typedef __attribute__((ext_vector_type(4))) int int4v;
typedef __attribute__((ext_vector_type(4))) unsigned uint4v;

// ---- bf16 helpers (RNE) ----
__device__ inline unsigned short f2bf(float f) {
    union { float f; unsigned u; } t; t.f = f;
    unsigned r = (t.u + 0x7fffu + ((t.u >> 16) & 1u)) >> 16;
    return (unsigned short)r;
}
__device__ inline float bf2f(unsigned short h) {
    union { unsigned u; float f; } t; t.u = ((unsigned)h) << 16; return t.f;
}
__device__ inline unsigned pack_bf16x2(float a, float b) {
    return (unsigned)f2bf(a) | ((unsigned)f2bf(b) << 16);
}
__device__ inline float bf_lo(unsigned u) { union { unsigned u; float f; } t; t.u = u << 16; return t.f; }
__device__ inline float bf_hi(unsigned u) { union { unsigned u; float f; } t; t.u = u & 0xffff0000u; return t.f; }

// {lo,hi} f32 pair from one packed-bf16 uint
__device__ inline float2v bfpair(unsigned u) {
    float2v r;
    r[0] = bf_lo(u);
    r[1] = bf_hi(u);
    return r;
}
// packed f32 add: one instruction for both halves (v_pk_add_f32, gfx950)
__device__ inline float2v pk_add(float2v a, float2v b) {
    float2v d;
    asm("v_pk_add_f32 %0, %1, %2" : "=v"(d) : "v"(a), "v"(b));
    return d;
}

// ---------------- cursor init + zero the dummy gather row (row N of HS tables) ----------
__global__ void cursor_init_kernel(int* __restrict__ gcursor,
                                   unsigned* __restrict__ HS1, unsigned* __restrict__ HS2) {
    int b = blockIdx.x * blockDim.x + threadIdx.x;
    if (b < NBUCK) gcursor[b] = b * BUCKET_CAP;
    if (b < 32) HS1[(size_t)N_NODES * 32 + b] = 0u;   // dummy row for CSR padding
    if (b < 16) HS2[(size_t)N_NODES * 16 + b] = 0u;
}

// ---------------- fused: stage edges (blocks < NSTAGE)  ||  P = X@W1 fp32 (rest) --------
// Stage: record = src | ((dst & 127) << 17); bucket-major LDS reorder then mostly-coalesced
// stream-out (identical to R6). GEMM blocks co-schedule in stage's idle issue slots
// (stage is latency/barrier-bound at ~2 blocks/CU) -- layer-1 GEMM runs for free.
// P holds X@W1 WITHOUT dinv (fp32, exact); bucket_csr applies dinv and packs to bf16,
// so the final HS1 bits are identical to the old separate linear kernel.
__global__ void __launch_bounds__(STAGE_TPB) stage_gemm_kernel(
    const int* __restrict__ src, const int* __restrict__ dst,
    int* __restrict__ gcursor, unsigned* __restrict__ staged,
    const float* __restrict__ X, const float* __restrict__ W,
    float* __restrict__ P, int E, int n) {
    const int tid = threadIdx.x;
    if (blockIdx.x < NSTAGE) {
        __shared__ int hist[NREP][NBUCK];      // counts, then block-local LDS write cursors
        __shared__ int dbase[NBUCK];           // global_base - lds_exclusive  per bucket
        __shared__ int scanw[1024];            // scan workspace (inclusive totals)
        __shared__ unsigned lrec[STAGE_CHUNK];
        __shared__ int laddr[STAGE_CHUNK];
        const int rep = (tid >> 8) & (NREP - 1);
        const int e0 = blockIdx.x * STAGE_CHUNK;
        for (int i = tid; i < NREP * NBUCK; i += STAGE_TPB) ((int*)hist)[i] = 0;
        scanw[tid] = 0; scanw[tid + 512] = 0;
        __syncthreads();
        int d[STAGE_EPT], s[STAGE_EPT];
#pragma unroll
        for (int k = 0; k < STAGE_EPT / 4; ++k) {
            int e = e0 + (k * STAGE_TPB + tid) * 4;
            if (e < E) {  // E % 4 == 0 so a valid group is fully in range
                int4v sv = __builtin_nontemporal_load((const int4v*)(src + e));
                int4v dv = __builtin_nontemporal_load((const int4v*)(dst + e));
#pragma unroll
                for (int i = 0; i < 4; ++i) {
                    s[4 * k + i] = sv[i];
                    d[4 * k + i] = dv[i];
                    atomicAdd(&hist[rep][dv[i] >> BSHIFT], 1);
                }
            } else {
#pragma unroll
                for (int i = 0; i < 4; ++i) d[4 * k + i] = -1;
            }
        }
        __syncthreads();
        // inclusive scan of per-bucket totals over 1024 slots (2/thread, Hillis-Steele)
        for (int i = tid; i < NBUCK; i += STAGE_TPB) scanw[i] = hist[0][i] + hist[1][i];
        if (tid + 512 < NBUCK) scanw[tid + 512] = hist[0][tid + 512] + hist[1][tid + 512];
        __syncthreads();
        for (int off = 1; off < 1024; off <<= 1) {
            int v0 = (tid >= off) ? scanw[tid - off] : 0;
            int v1 = (tid + 512 >= off) ? scanw[tid + 512 - off] : 0;
            __syncthreads();
            scanw[tid] += v0;
            scanw[tid + 512] += v1;
            __syncthreads();
        }
        // reserve global space, convert hist -> block-local LDS cursors, record addr delta
        for (int i = tid; i < NBUCK; i += STAGE_TPB) {
            int h0 = hist[0][i], h1 = hist[1][i];
            int t = h0 + h1;
            int excl = scanw[i] - t;
            if (t > 0) {
                int g = atomicAdd(&gcursor[i], t);
                dbase[i] = g - excl;
            }
            hist[0][i] = excl;
            hist[1][i] = excl + h0;
        }
        __syncthreads();
        // place records bucket-major in LDS, remembering each slot's global address
#pragma unroll
        for (int k = 0; k < STAGE_EPT; ++k) {
            if (d[k] >= 0) {
                int b = d[k] >> BSHIFT;
                int slot = atomicAdd(&hist[rep][b], 1);
                lrec[slot] = (unsigned)s[k] | ((unsigned)(d[k] & (BSIZE - 1)) << 17);
                laddr[slot] = dbase[b] + slot;
            }
        }
        __syncthreads();
        // stream out: piecewise-contiguous global addresses -> mostly-coalesced stores
        const int total = min(STAGE_CHUNK, E - e0);
        for (int i = tid; i < total; i += STAGE_TPB) {
            int a = laddr[i];
            if ((unsigned)a < (unsigned)(NBUCK * BUCKET_CAP))  // safety clamp (never trips)
                staged[a] = lrec[i];
        }
    } else {
        // ---- fused GEMM: P = X@W1 fp32, split-bf16 MFMA (identical math to old linear) --
        constexpr int NT = 4;                 // FOUT = 64
        const int NTILES_M = n / 16;
        const int lane = tid & 63;
        const int gwave = (blockIdx.x - NSTAGE) * 8 + (tid >> 6);
        const int nwaves = NGEMM * 8;
        const int m = lane & 15;
        const int q = lane >> 4;
        short8 Bhi[2][NT], Blo[2][NT];
#pragma unroll
        for (int ks = 0; ks < 2; ++ks)
#pragma unroll
            for (int nt = 0; nt < NT; ++nt) {
                short8 bh, bl;
#pragma unroll
                for (int j = 0; j < 8; ++j) {
                    int k = ks * 32 + q * 8 + j;
                    float wv = W[k * 64 + nt * 16 + m];
                    unsigned short h = f2bf(wv);
                    bh[j] = (short)h;
                    bl[j] = (short)f2bf(wv - bf2f(h));
                }
                Bhi[ks][nt] = bh;
                Blo[ks][nt] = bl;
            }
        for (int tile = gwave; tile < NTILES_M; tile += nwaves) {
            const int row0 = tile * 16;
            float4v C[NT];
#pragma unroll
            for (int nt = 0; nt < NT; ++nt) C[nt] = (float4v){0.f, 0.f, 0.f, 0.f};
#pragma unroll
            for (int ks = 0; ks < 2; ++ks) {
                const float* xp = X + (size_t)(row0 + m) * 64 + ks * 32 + q * 8;
                float4v x0 = __builtin_nontemporal_load((const float4v*)xp);
                float4v x1 = __builtin_nontemporal_load((const float4v*)(xp + 4));
                short8 Ahi, Alo;
#pragma unroll
                for (int j = 0; j < 4; ++j) {
                    unsigned short h0 = f2bf(x0[j]);
                    Ahi[j] = (short)h0;
                    Alo[j] = (short)f2bf(x0[j] - bf2f(h0));
                    unsigned short h1 = f2bf(x1[j]);
                    Ahi[4 + j] = (short)h1;
                    Alo[4 + j] = (short)f2bf(x1[j] - bf2f(h1));
                }
#pragma unroll
                for (int nt = 0; nt < NT; ++nt) {
                    C[nt] = __builtin_amdgcn_mfma_f32_16x16x32_bf16(Ahi, Bhi[ks][nt], C[nt], 0, 0, 0);
                    C[nt] = __builtin_amdgcn_mfma_f32_16x16x32_bf16(Alo, Bhi[ks][nt], C[nt], 0, 0, 0);
                    C[nt] = __builtin_amdgcn_mfma_f32_16x16x32_bf16(Ahi, Blo[ks][nt], C[nt], 0, 0, 0);
                }
            }
#pragma unroll
            for (int nt = 0; nt < NT; ++nt)
#pragma unroll
                for (int reg = 0; reg < 4; ++reg)
                    P[(size_t)(row0 + q * 4 + reg) * 64 + nt * 16 + m] = C[nt][reg];
        }
    }
}

// ---------------- per-bucket: meta/dinv + fine CSR + HS1 = bf16(P*dinv) ------------------
// csrc region for bucket b = [b*CSR_STRIDE, ...). meta[gslot] = {edge_start, real_deg,
// node, dinv_bits}; slots degree-sorted within the bucket. Pad slots -> src = N_NODES.
// Tail folds the layer-1 scaling: HS1[node] = bf16x2(P[node]*dinv) in the interleaved
// gather layout (uint ch*16+c packs feats (32ch+c, 32ch+16+c)) -- absorbed into this
// latency-bound kernel; bit-identical to the old separate linear epilogue.
__global__ void bucket_csr_kernel(const unsigned* __restrict__ staged,
                                  const int* __restrict__ gcursor,
                                  const float* __restrict__ P,
                                  int4v* __restrict__ meta, float* __restrict__ dinv,
                                  int* __restrict__ csrc, unsigned* __restrict__ HS1, int n) {
    __shared__ int ldeg[BSIZE];
    __shared__ int laex[BSIZE];
    __shared__ int lscan[BSIZE];
    __shared__ int lcnt[BSIZE];
    __shared__ float ldv[BSIZE];
    __shared__ int h2[32];
    __shared__ int c2[32];
    __shared__ unsigned lrec[BUCKET_CAP];
    __shared__ int lsrc[BUCKET_CAP + 512];
    __shared__ int ltot;
    const int b = blockIdx.x;
    const int node0 = b * BSIZE;
    const int nn = min(BSIZE, n - node0);
    const int tid = threadIdx.x;  // 256
    if (tid < BSIZE) { ldeg[tid] = 0; lcnt[tid] = 0; }
    if (tid < 32) { h2[tid] = 0; c2[tid] = 0; }
    __syncthreads();
    const int ebase = b * CSR_STRIDE;
    int ecnt = gcursor[b] - b * BUCKET_CAP;
    if (ecnt > BUCKET_CAP) ecnt = BUCKET_CAP;
    const int sbase = b * BUCKET_CAP;
    for (int i = tid; i < ecnt; i += 256) {
        unsigned r = staged[sbase + i];
        lrec[i] = r;
        atomicAdd(&ldeg[(r >> 17) & (BSIZE - 1)], 1);
    }
    __syncthreads();
    int mydeg = (tid < BSIZE) ? ldeg[tid] : 0;
    int adeg = (mydeg + 3) & ~3;               // 4-aligned degree
    if (tid < BSIZE) lscan[tid] = adeg;
    __syncthreads();
    for (int off = 1; off < BSIZE; off <<= 1) {
        int v = 0;
        if (tid < BSIZE && tid >= off) v = lscan[tid - off];
        __syncthreads();
        if (tid < BSIZE) lscan[tid] += v;
        __syncthreads();
    }
    const int bin = min(adeg >> 2, 31);
    float mydinv = 0.0f;
    if (tid < BSIZE) {
        int aex = lscan[tid] - adeg;  // exclusive over aligned degrees
        laex[tid] = aex;
        if (tid == BSIZE - 1) ltot = lscan[tid];
        if (tid < nn) {
            mydinv = rsqrtf((float)mydeg + 2.0f);
            dinv[node0 + tid] = mydinv;
            ldv[tid] = mydinv;
            for (int k = mydeg; k < adeg; ++k) lsrc[aex + k] = N_NODES;  // pad -> zero row
            atomicAdd(&h2[bin], 1);
        }
    }
    __syncthreads();
    if (tid == 0) {  // exclusive scan of 32 bins
        int acc = 0;
        for (int k = 0; k < 32; ++k) { int v = h2[k]; h2[k] = acc; acc += v; }
    }
    __syncthreads();
    if (tid < nn) {
        int pos = h2[bin] + atomicAdd(&c2[bin], 1);
        union { float f; int i; } dv; dv.f = mydinv;
        meta[node0 + pos] = (int4v){ebase + laex[tid], mydeg, node0 + tid, dv.i};
    }
    for (int i = tid; i < ecnt; i += 256) {
        unsigned r = lrec[i];
        int dl = (int)((r >> 17) & (BSIZE - 1));
        int sv = (int)(r & 0x1FFFFu);
        int pos = laex[dl] + atomicAdd(&lcnt[dl], 1);
        if (pos < BUCKET_CAP + 512) lsrc[pos] = sv;
    }
    __syncthreads();
    const int tot = ltot;
    for (int i = tid; i < tot; i += 256)
        csrc[ebase + i] = lsrc[i];
    // ---- tail: HS1 rows for this bucket (2 threads/node: half h covers uints 16h..16h+15)
    for (int i = tid; i < nn * 2; i += 256) {
        const int nloc = i >> 1, h = i & 1;
        const int node = node0 + nloc;
        const float di = ldv[nloc];
        const float* pr = P + (size_t)node * 64 + 32 * h;
        unsigned* op = HS1 + (size_t)node * 32 + 16 * h;
#pragma unroll
        for (int c0 = 0; c0 < 16; c0 += 4) {
            float4v lo = *(const float4v*)(pr + c0);
            float4v hi = *(const float4v*)(pr + 16 + c0);
            uint4v u;
#pragma unroll
            for (int k = 0; k < 4; ++k) u[k] = pack_bf16x2(lo[k] * di, hi[k] * di);
            __builtin_nontemporal_store(u, (uint4v*)(op + c0));
        }
    }
}

// ---------------- MFMA linear (layer 2 only): HS = bf16x2((X@W)*dinv) --------------------
// One row of NT*8 uints per node; uint (ch*16+c) packs (feat 32ch+c, feat 32ch+16+c).
template <int FOUT>   // 32
__global__ void __launch_bounds__(256) linear_mfma_kernel(
    const float* __restrict__ X, const float* __restrict__ W,
    const float* __restrict__ dinv, unsigned* __restrict__ HS, int n) {
    constexpr int NT = FOUT / 16;            // n-tiles
    constexpr int ROWU = NT * 8;             // uints per node row
    const int NTILES_M = n / 16;             // 6250 (n divisible by 16)
    const int lane = threadIdx.x & 63;
    const int gwave = blockIdx.x * 4 + (threadIdx.x >> 6);
    const int nwaves = gridDim.x * 4;
    const int m = lane & 15;
    const int q = lane >> 4;  // 0..3

    short8 Bhi[2][NT], Blo[2][NT];
#pragma unroll
    for (int ks = 0; ks < 2; ++ks)
#pragma unroll
        for (int nt = 0; nt < NT; ++nt) {
            short8 bh, bl;
#pragma unroll
            for (int j = 0; j < 8; ++j) {
                int k = ks * 32 + q * 8 + j;
                float wv = W[k * FOUT + nt * 16 + m];
                unsigned short h = f2bf(wv);
                bh[j] = (short)h;
                bl[j] = (short)f2bf(wv - bf2f(h));
            }
            Bhi[ks][nt] = bh;
            Blo[ks][nt] = bl;
        }

    for (int tile = gwave; tile < NTILES_M; tile += nwaves) {
        const int row0 = tile * 16;
        float4v C[NT];
#pragma unroll
        for (int nt = 0; nt < NT; ++nt) C[nt] = (float4v){0.f, 0.f, 0.f, 0.f};
#pragma unroll
        for (int ks = 0; ks < 2; ++ks) {
            const float* xp = X + (size_t)(row0 + m) * 64 + ks * 32 + q * 8;
            float4v x0 = __builtin_nontemporal_load((const float4v*)xp);
            float4v x1 = __builtin_nontemporal_load((const float4v*)(xp + 4));
            short8 Ahi, Alo;
#pragma unroll
            for (int j = 0; j < 4; ++j) {
                unsigned short h0 = f2bf(x0[j]);
                Ahi[j] = (short)h0;
                Alo[j] = (short)f2bf(x0[j] - bf2f(h0));
                unsigned short h1 = f2bf(x1[j]);
                Ahi[4 + j] = (short)h1;
                Alo[4 + j] = (short)f2bf(x1[j] - bf2f(h1));
            }
#pragma unroll
            for (int nt = 0; nt < NT; ++nt) {
                C[nt] = __builtin_amdgcn_mfma_f32_16x16x32_bf16(Ahi, Bhi[ks][nt], C[nt], 0, 0, 0);
                C[nt] = __builtin_amdgcn_mfma_f32_16x16x32_bf16(Alo, Bhi[ks][nt], C[nt], 0, 0, 0);
                C[nt] = __builtin_amdgcn_mfma_f32_16x16x32_bf16(Ahi, Blo[ks][nt], C[nt], 0, 0, 0);
            }
        }
#pragma unroll
        for (int ch = 0; ch < NT / 2; ++ch) {
#pragma unroll
            for (int reg = 0; reg < 4; ++reg) {
                int r = row0 + q * 4 + reg;
                float di = dinv[r];
                unsigned u = pack_bf16x2(C[2 * ch][reg] * di, C[2 * ch + 1][reg] * di);
                __builtin_nontemporal_store(u, HS + (size_t)r * ROWU + ch * 16 + m);
            }
        }
    }
}

// ---------------- vectorized gather: dwordx4 HS rows + int4 csrc + int4 meta -------------
// ROWU uints per node row (32: layer1; 16: layer2). G = ROWU/4 lanes per node; lane t owns
// uints [4t,4t+4). Edge lists padded to a multiple of 4 with src = N_NODES (zero row).
// One broadcast int4 meta load per node supplies {start, deg, node, dinv}.
// Accumulation in packed f32 pairs via v_pk_add_f32.
template <int ROWU, bool RELU>
__global__ void __launch_bounds__(256) gather_vec_kernel(
    const int4v* __restrict__ meta, const int* __restrict__ csrc,
    const unsigned* __restrict__ HS, const float* __restrict__ bias,
    float* __restrict__ OUT, int n) {
    constexpr int G = ROWU / 4;          // lanes per node: 8 or 4
    constexpr int NPB = 256 / G;         // nodes per block: 32 or 64
    constexpr int FOUT = ROWU * 2;
    const int gslot = blockIdx.x * NPB + (int)(threadIdx.x / G);
    const int t = threadIdx.x % G;
    if (gslot >= n) return;
    const int4v mi = meta[gslot];
    const int start = mi[0];
    const int deg = mi[1];
    const int node = mi[2];
    union { int i; float f; } dv; dv.i = mi[3];
    const float dd = dv.f;
    const int pend = start + ((deg + 3) & ~3);
    const unsigned* __restrict__ HSt = HS + 4 * t;
    const uint4v own = *(const uint4v*)(HS + (size_t)node * ROWU + 4 * t);
    float2v acc[4];   // acc[k] = {lo, hi} accumulators for uint k of this lane's slice
#pragma unroll
    for (int k = 0; k < 4; ++k) {
        float2v o = bfpair(own[k]);
        acc[k][0] = 2.0f * o[0];
        acc[k][1] = 2.0f * o[1];
    }
    int j = start;
    for (; j + 8 <= pend; j += 8) {
        int4v s0 = __builtin_nontemporal_load((const int4v*)(csrc + j));
        int4v s1 = __builtin_nontemporal_load((const int4v*)(csrc + j + 4));
        uint4v u0 = *(const uint4v*)(HSt + (size_t)s0[0] * ROWU);
        uint4v u1 = *(const uint4v*)(HSt + (size_t)s0[1] * ROWU);
        uint4v u2 = *(const uint4v*)(HSt + (size_t)s0[2] * ROWU);
        uint4v u3 = *(const uint4v*)(HSt + (size_t)s0[3] * ROWU);
        uint4v u4 = *(const uint4v*)(HSt + (size_t)s1[0] * ROWU);
        uint4v u5 = *(const uint4v*)(HSt + (size_t)s1[1] * ROWU);
        uint4v u6 = *(const uint4v*)(HSt + (size_t)s1[2] * ROWU);
        uint4v u7 = *(const uint4v*)(HSt + (size_t)s1[3] * ROWU);
#pragma unroll
        for (int k = 0; k < 4; ++k) {
            float2v p01 = pk_add(bfpair(u0[k]), bfpair(u1[k]));
            float2v p23 = pk_add(bfpair(u2[k]), bfpair(u3[k]));
            float2v p45 = pk_add(bfpair(u4[k]), bfpair(u5[k]));
            float2v p67 = pk_add(bfpair(u6[k]), bfpair(u7[k]));
            acc[k] = pk_add(acc[k], pk_add(pk_add(p01, p23), pk_add(p45, p67)));
        }
    }
    if (j < pend) {  // exactly one group of 4 (padded counts are multiples of 4)
        int4v s0 = __builtin_nontemporal_load((const int4v*)(csrc + j));
        uint4v u0 = *(const uint4v*)(HSt + (size_t)s0[0] * ROWU);
        uint4v u1 = *(const uint4v*)(HSt + (size_t)s0[1] * ROWU);
        uint4v u2 = *(const uint4v*)(HSt + (size_t)s0[2] * ROWU);
        uint4v u3 = *(const uint4v*)(HSt + (size_t)s0[3] * ROWU);
#pragma unroll
        for (int k = 0; k < 4; ++k) {
            float2v p01 = pk_add(bfpair(u0[k]), bfpair(u1[k]));
            float2v p23 = pk_add(bfpair(u2[k]), bfpair(u3[k]));
            acc[k] = pk_add(acc[k], pk_add(p01, p23));
        }
    }
    const int ch = t >> 2;               // 0 when ROWU==16
    const int c0 = (4 * t) & 15;
    const float4v blv = *(const float4v*)(bias + 32 * ch + c0);
    const float4v bhv = *(const float4v*)(bias + 32 * ch + 16 + c0);
    float4v olo, ohi;
#pragma unroll
    for (int k = 0; k < 4; ++k) {
        float o0 = acc[k][0] * dd + blv[k];
        float o1 = acc[k][1] * dd + bhv[k];
        if (RELU) { o0 = fmaxf(o0, 0.0f); o1 = fmaxf(o1, 0.0f); }
        olo[k] = o0;
        ohi[k] = o1;
    }
    float* op = OUT + (size_t)node * FOUT + 32 * ch + c0;
    __builtin_nontemporal_store(olo, (float4v*)op);
    __builtin_nontemporal_store(ohi, (float4v*)(op + 16));
}

extern "C" void kernel_launch(void* const* d_in, const int* in_sizes, int n_in,
                              void* d_out, int out_size, void* d_ws, size_t ws_size,
                              hipStream_t stream) {
    const float* x  = (const float*)d_in[0];   // [N,64]
    const int*   ei = (const int*)d_in[1];     // [2,E] row-major: src then dst
    const float* W1 = (const float*)d_in[2];   // [64,64]
    const float* b1 = (const float*)d_in[3];   // [64]
    const float* W2 = (const float*)d_in[4];   // [64,32]
    const float* b2 = (const float*)d_in[5];   // [32]

    const int* srcp = ei;
    const int* dstp = ei + E_EDGES;

    // tuple return order: (out [N,32], feature_map [N,64]) concatenated flat
    float* out = (float*)d_out;                   // N*32
    float* fm  = (float*)d_out + N_NODES * 32;    // N*64 (also h1 input to layer 2)

    // workspace layout, every array 256B-aligned (HS rows must not straddle 64B lines)
    char* w = (char*)d_ws;
    auto alloc = [&w](size_t bytes) -> void* {
        uintptr_t p = ((uintptr_t)w + 255) & ~(uintptr_t)255;
        w = (char*)(p + bytes);
        return (void*)p;
    };
    int*      gcursor  = (int*)alloc(sizeof(int) * NBUCK);
    int4v*    meta     = (int4v*)alloc(sizeof(int4v) * N_NODES);
    float*    dinv     = (float*)alloc(sizeof(float) * N_NODES);
    float*    P        = (float*)alloc(sizeof(float) * (size_t)N_NODES * 64);  // X@W1 fp32
    int*      csrc     = (int*)alloc(sizeof(int) * (size_t)NBUCK * CSR_STRIDE);
    unsigned* staged   = (unsigned*)alloc(sizeof(unsigned) * (size_t)NBUCK * BUCKET_CAP);
    unsigned* HS1      = (unsigned*)alloc(sizeof(unsigned) * (size_t)(N_NODES + 1) * 32);
    unsigned* HS2      = (unsigned*)alloc(sizeof(unsigned) * (size_t)(N_NODES + 1) * 16);

    // ---- preprocessing + layer-1 GEMM fused (GEMM hides under stage's latency) ----
    cursor_init_kernel<<<(NBUCK + 255) / 256, 256, 0, stream>>>(gcursor, HS1, HS2);
    stage_gemm_kernel<<<NSTAGE + NGEMM, STAGE_TPB, 0, stream>>>(
        srcp, dstp, gcursor, staged, x, W1, P, E_EDGES, N_NODES);
    bucket_csr_kernel<<<NBUCK, 256, 0, stream>>>(staged, gcursor, P, meta, dinv, csrc,
                                                 HS1, N_NODES);

    // ---- layer 1 gather: fm = relu(A_hat @ HS1 + b1), 128B rows ----
    gather_vec_kernel<32, true><<<(N_NODES + 31) / 32, 256, 0, stream>>>(
        meta, csrc, HS1, b1, fm, N_NODES);

    // ---- layer 2: HS2 = bf16((fm@W2)*dinv) via MFMA; out = gather, 64B rows ----
    linear_mfma_kernel<32><<<512, 256, 0, stream>>>(fm, W2, dinv, HS2, N_NODES);
    gather_vec_kernel<16, false><<<(N_NODES + 63) / 64, 256, 0, stream>>>(
        meta, csrc, HS2, b2, out, N_NODES);
}

// Round 8
// 197.083 us; speedup vs baseline: 1.0982x; 1.0982x over previous
//
#include <hip/hip_runtime.h>

#define N_NODES 100000
#define E_EDGES 1600000

// bucketed CSR build
#define BSHIFT 7
#define BSIZE 128
#define NBUCK ((N_NODES + BSIZE - 1) / BSIZE)           // 782
#define STAGE_TPB 512
#define STAGE_EPT 8
#define STAGE_CHUNK (STAGE_TPB * STAGE_EPT)             // 4096
#define NREP 2                                           // LDS histogram replicas in stage
#define BUCKET_CAP 4096                                  // staged slots per bucket (mean 2046)
#define CSR_STRIDE (BUCKET_CAP + 512)                    // fixed csrc ints per bucket (4-aligned)

typedef __attribute__((ext_vector_type(8))) short short8;
typedef __attribute__((ext_vector_type(4))) float float4v;
typedef __attribute__((ext_vector_type(2))) float float2v;
typedef __attribute__((ext_vector_type(4))) int int4v;
typedef __attribute__((ext_vector_type(4))) unsigned uint4v;

// ---- bf16 helpers (RNE) ----
__device__ inline unsigned short f2bf(float f) {
    union { float f; unsigned u; } t; t.f = f;
    unsigned r = (t.u + 0x7fffu + ((t.u >> 16) & 1u)) >> 16;
    return (unsigned short)r;
}
__device__ inline float bf2f(unsigned short h) {
    union { unsigned u; float f; } t; t.u = ((unsigned)h) << 16; return t.f;
}
__device__ inline unsigned pack_bf16x2(float a, float b) {
    return (unsigned)f2bf(a) | ((unsigned)f2bf(b) << 16);
}
__device__ inline float bf_lo(unsigned u) { union { unsigned u; float f; } t; t.u = u << 16; return t.f; }
__device__ inline float bf_hi(unsigned u) { union { unsigned u; float f; } t; t.u = u & 0xffff0000u; return t.f; }

// {lo,hi} f32 pair from one packed-bf16 uint (2 VALU ops)
__device__ inline float2v bfpair(unsigned u) {
    float2v r;
    r[0] = bf_lo(u);
    r[1] = bf_hi(u);
    return r;
}
// packed f32 add: one instruction for both halves (v_pk_add_f32, gfx950)
__device__ inline float2v pk_add(float2v a, float2v b) {
    float2v d;
    asm("v_pk_add_f32 %0, %1, %2" : "=v"(d) : "v"(a), "v"(b));
    return d;
}

// ---------------- cursor init + zero the dummy gather row (row N of HS tables) ----------
__global__ void cursor_init_kernel(int* __restrict__ gcursor,
                                   unsigned* __restrict__ HS1, unsigned* __restrict__ HS2) {
    int b = blockIdx.x * blockDim.x + threadIdx.x;
    if (b < NBUCK) gcursor[b] = b * BUCKET_CAP;
    if (b < 32) HS1[(size_t)N_NODES * 32 + b] = 0u;   // dummy row for CSR padding
    if (b < 16) HS2[(size_t)N_NODES * 16 + b] = 0u;
}

// ---------------- stage edges -> bucket regions, LDS bucket-major reorder ----------------
// record = src | ((dst & 127) << 17); src < 2^17.
// Records are sorted into bucket-major order in LDS (block-local scan gives slot + exact
// global address), then streamed out linearly: consecutive LDS slots -> consecutive global
// addresses within each per-bucket run, so a wave's 64 stores span ~12 lines, not 64.
__global__ void __launch_bounds__(STAGE_TPB) stage_kernel(
    const int* __restrict__ src, const int* __restrict__ dst,
    int* __restrict__ gcursor, unsigned* __restrict__ staged, int E) {
    __shared__ int hist[NREP][NBUCK];      // counts, then block-local LDS write cursors
    __shared__ int dbase[NBUCK];           // global_base - lds_exclusive  per bucket
    __shared__ int scanw[1024];            // scan workspace (inclusive totals)
    __shared__ unsigned lrec[STAGE_CHUNK];
    __shared__ int laddr[STAGE_CHUNK];
    const int tid = threadIdx.x;
    const int rep = (tid >> 8) & (NREP - 1);
    const int e0 = blockIdx.x * STAGE_CHUNK;
    for (int i = tid; i < NREP * NBUCK; i += STAGE_TPB) ((int*)hist)[i] = 0;
    scanw[tid] = 0; scanw[tid + 512] = 0;
    __syncthreads();
    int d[STAGE_EPT], s[STAGE_EPT];
#pragma unroll
    for (int k = 0; k < STAGE_EPT / 4; ++k) {
        int e = e0 + (k * STAGE_TPB + tid) * 4;
        if (e < E) {  // E % 4 == 0 so a valid group is fully in range
            int4v sv = __builtin_nontemporal_load((const int4v*)(src + e));
            int4v dv = __builtin_nontemporal_load((const int4v*)(dst + e));
#pragma unroll
            for (int i = 0; i < 4; ++i) {
                s[4 * k + i] = sv[i];
                d[4 * k + i] = dv[i];
                atomicAdd(&hist[rep][dv[i] >> BSHIFT], 1);
            }
        } else {
#pragma unroll
            for (int i = 0; i < 4; ++i) d[4 * k + i] = -1;
        }
    }
    __syncthreads();
    // inclusive scan of per-bucket totals over 1024 slots (2 per thread, Hillis-Steele)
    for (int i = tid; i < NBUCK; i += STAGE_TPB) scanw[i] = hist[0][i] + hist[1][i];
    if (tid + 512 < NBUCK) scanw[tid + 512] = hist[0][tid + 512] + hist[1][tid + 512];
    __syncthreads();
    for (int off = 1; off < 1024; off <<= 1) {
        int v0 = (tid >= off) ? scanw[tid - off] : 0;
        int v1 = (tid + 512 >= off) ? scanw[tid + 512 - off] : 0;
        __syncthreads();
        scanw[tid] += v0;
        scanw[tid + 512] += v1;
        __syncthreads();
    }
    // reserve global space, convert hist -> block-local LDS cursors, record addr delta
    for (int i = tid; i < NBUCK; i += STAGE_TPB) {
        int h0 = hist[0][i], h1 = hist[1][i];
        int t = h0 + h1;
        int excl = scanw[i] - t;
        if (t > 0) {
            int g = atomicAdd(&gcursor[i], t);
            dbase[i] = g - excl;
        }
        hist[0][i] = excl;
        hist[1][i] = excl + h0;
    }
    __syncthreads();
    // place records bucket-major in LDS, remembering each slot's global address
#pragma unroll
    for (int k = 0; k < STAGE_EPT; ++k) {
        if (d[k] >= 0) {
            int b = d[k] >> BSHIFT;
            int slot = atomicAdd(&hist[rep][b], 1);
            lrec[slot] = (unsigned)s[k] | ((unsigned)(d[k] & (BSIZE - 1)) << 17);
            laddr[slot] = dbase[b] + slot;
        }
    }
    __syncthreads();
    // stream out: piecewise-contiguous global addresses -> mostly-coalesced stores
    const int total = min(STAGE_CHUNK, E - e0);
    for (int i = tid; i < total; i += STAGE_TPB) {
        int a = laddr[i];
        if ((unsigned)a < (unsigned)(NBUCK * BUCKET_CAP))  // safety clamp (never trips)
            staged[a] = lrec[i];
    }
}

// ---------------- per-bucket: meta/dinv + fine CSR (fixed stride, 4-aligned per node) ----
// csrc region for bucket b = [b*CSR_STRIDE, ...) -- no global scan needed.
// meta[gslot] = {edge_start, real_deg, node, dinv_bits}: gathers read ONE broadcast int4
// per node. Slots are degree-sorted within the bucket (counting sort) so a gather wave's
// node-groups have near-equal trip counts. Pad slots hold src = N_NODES (zero row).
__global__ void bucket_csr_kernel(const unsigned* __restrict__ staged,
                                  const int* __restrict__ gcursor,
                                  int4v* __restrict__ meta, float* __restrict__ dinv,
                                  int* __restrict__ csrc, int n) {
    __shared__ int ldeg[BSIZE];
    __shared__ int laex[BSIZE];
    __shared__ int lscan[BSIZE];
    __shared__ int lcnt[BSIZE];
    __shared__ int h2[32];
    __shared__ int c2[32];
    __shared__ unsigned lrec[BUCKET_CAP];
    __shared__ int lsrc[BUCKET_CAP + 512];
    __shared__ int ltot;
    const int b = blockIdx.x;
    const int node0 = b * BSIZE;
    const int nn = min(BSIZE, n - node0);
    const int tid = threadIdx.x;  // 256
    if (tid < BSIZE) { ldeg[tid] = 0; lcnt[tid] = 0; }
    if (tid < 32) { h2[tid] = 0; c2[tid] = 0; }
    __syncthreads();
    const int ebase = b * CSR_STRIDE;
    int ecnt = gcursor[b] - b * BUCKET_CAP;
    if (ecnt > BUCKET_CAP) ecnt = BUCKET_CAP;
    const int sbase = b * BUCKET_CAP;
    for (int i = tid; i < ecnt; i += 256) {
        unsigned r = staged[sbase + i];
        lrec[i] = r;
        atomicAdd(&ldeg[(r >> 17) & (BSIZE - 1)], 1);
    }
    __syncthreads();
    int mydeg = (tid < BSIZE) ? ldeg[tid] : 0;
    int adeg = (mydeg + 3) & ~3;               // 4-aligned degree
    if (tid < BSIZE) lscan[tid] = adeg;
    __syncthreads();
    for (int off = 1; off < BSIZE; off <<= 1) {
        int v = 0;
        if (tid < BSIZE && tid >= off) v = lscan[tid - off];
        __syncthreads();
        if (tid < BSIZE) lscan[tid] += v;
        __syncthreads();
    }
    const int bin = min(adeg >> 2, 31);
    float mydinv = 0.0f;
    if (tid < BSIZE) {
        int aex = lscan[tid] - adeg;  // exclusive over aligned degrees
        laex[tid] = aex;
        if (tid == BSIZE - 1) ltot = lscan[tid];
        if (tid < nn) {
            mydinv = rsqrtf((float)mydeg + 2.0f);
            dinv[node0 + tid] = mydinv;
            for (int k = mydeg; k < adeg; ++k) lsrc[aex + k] = N_NODES;  // pad -> zero row
            atomicAdd(&h2[bin], 1);
        }
    }
    __syncthreads();
    if (tid == 0) {  // exclusive scan of 32 bins
        int acc = 0;
        for (int k = 0; k < 32; ++k) { int v = h2[k]; h2[k] = acc; acc += v; }
    }
    __syncthreads();
    if (tid < nn) {
        int pos = h2[bin] + atomicAdd(&c2[bin], 1);
        union { float f; int i; } dv; dv.f = mydinv;
        meta[node0 + pos] = (int4v){ebase + laex[tid], mydeg, node0 + tid, dv.i};
    }
    for (int i = tid; i < ecnt; i += 256) {
        unsigned r = lrec[i];
        int dl = (int)((r >> 17) & (BSIZE - 1));
        int sv = (int)(r & 0x1FFFFu);
        int pos = laex[dl] + atomicAdd(&lcnt[dl], 1);
        if (pos < BUCKET_CAP + 512) lsrc[pos] = sv;
    }
    __syncthreads();
    const int tot = ltot;
    for (int i = tid; i < tot; i += 256)
        csrc[ebase + i] = lsrc[i];
}

// ---------------- MFMA linear: HS = bf16x2((X@W)*dinv), interleaved row layout ----------
// Split GEMM: Ahi*Whi + Alo*Whi + Ahi*Blo gives ~fp32 accuracy with bf16 MFMA.
// C/D layout (16x16x32_bf16): col=lane&15, row=(lane>>4)*4+reg.  A: [m=lane&15][k=(lane>>4)*8+j].
// One row of NT*8 uints per node; uint (ch*16+c) packs (feat 32ch+c, feat 32ch+16+c).
// Row = 128B (FOUT=64) or 64B (FOUT=32): the gather consumes whole lines with dwordx4.
template <int FOUT>   // 64 or 32
__global__ void __launch_bounds__(256) linear_mfma_kernel(
    const float* __restrict__ X, const float* __restrict__ W,
    const float* __restrict__ dinv, unsigned* __restrict__ HS, int n) {
    constexpr int NT = FOUT / 16;            // n-tiles
    constexpr int ROWU = NT * 8;             // uints per node row
    const int NTILES_M = n / 16;             // 6250 (n divisible by 16)
    const int lane = threadIdx.x & 63;
    const int gwave = blockIdx.x * 4 + (threadIdx.x >> 6);
    const int nwaves = gridDim.x * 4;
    const int m = lane & 15;
    const int q = lane >> 4;  // 0..3

    // W fragments in registers (hi+lo), loaded once per wave
    short8 Bhi[2][NT], Blo[2][NT];
#pragma unroll
    for (int ks = 0; ks < 2; ++ks)
#pragma unroll
        for (int nt = 0; nt < NT; ++nt) {
            short8 bh, bl;
#pragma unroll
            for (int j = 0; j < 8; ++j) {
                int k = ks * 32 + q * 8 + j;
                float wv = W[k * FOUT + nt * 16 + m];
                unsigned short h = f2bf(wv);
                bh[j] = (short)h;
                bl[j] = (short)f2bf(wv - bf2f(h));
            }
            Bhi[ks][nt] = bh;
            Blo[ks][nt] = bl;
        }

    for (int tile = gwave; tile < NTILES_M; tile += nwaves) {
        const int row0 = tile * 16;
        float4v C[NT];
#pragma unroll
        for (int nt = 0; nt < NT; ++nt) C[nt] = (float4v){0.f, 0.f, 0.f, 0.f};
#pragma unroll
        for (int ks = 0; ks < 2; ++ks) {
            const float* xp = X + (size_t)(row0 + m) * 64 + ks * 32 + q * 8;
            float4v x0 = __builtin_nontemporal_load((const float4v*)xp);
            float4v x1 = __builtin_nontemporal_load((const float4v*)(xp + 4));
            short8 Ahi, Alo;
#pragma unroll
            for (int j = 0; j < 4; ++j) {
                unsigned short h0 = f2bf(x0[j]);
                Ahi[j] = (short)h0;
                Alo[j] = (short)f2bf(x0[j] - bf2f(h0));
                unsigned short h1 = f2bf(x1[j]);
                Ahi[4 + j] = (short)h1;
                Alo[4 + j] = (short)f2bf(x1[j] - bf2f(h1));
            }
#pragma unroll
            for (int nt = 0; nt < NT; ++nt) {
                C[nt] = __builtin_amdgcn_mfma_f32_16x16x32_bf16(Ahi, Bhi[ks][nt], C[nt], 0, 0, 0);
                C[nt] = __builtin_amdgcn_mfma_f32_16x16x32_bf16(Alo, Bhi[ks][nt], C[nt], 0, 0, 0);
                C[nt] = __builtin_amdgcn_mfma_f32_16x16x32_bf16(Ahi, Blo[ks][nt], C[nt], 0, 0, 0);
            }
        }
        // epilogue: pair n-tile 2ch (cols 0-15) with 2ch+1 (cols 16-31) into interleaved row
#pragma unroll
        for (int ch = 0; ch < NT / 2; ++ch) {
#pragma unroll
            for (int reg = 0; reg < 4; ++reg) {
                int r = row0 + q * 4 + reg;
                float di = dinv[r];
                unsigned u = pack_bf16x2(C[2 * ch][reg] * di, C[2 * ch + 1][reg] * di);
                __builtin_nontemporal_store(u, HS + (size_t)r * ROWU + ch * 16 + m);
            }
        }
    }
}

// ---------------- vectorized gather: dwordx4 HS rows + int4 csrc + int4 meta -------------
// ROWU uints per node row (32: layer1; 16: layer2). G = ROWU/4 lanes per node; lane t owns
// uints [4t,4t+4). Edge lists padded to a multiple of 4 with src = N_NODES (zero row), so
// the inner loop is pure int4 csrc loads + dwordx4 gathers. One broadcast int4 meta load
// per node supplies {start, deg, node, dinv}.
// Accumulation in packed f32 pairs via v_pk_add_f32 (3 VALU ops per gathered uint).
template <int ROWU, bool RELU>
__global__ void __launch_bounds__(256) gather_vec_kernel(
    const int4v* __restrict__ meta, const int* __restrict__ csrc,
    const unsigned* __restrict__ HS, const float* __restrict__ bias,
    float* __restrict__ OUT, int n) {
    constexpr int G = ROWU / 4;          // lanes per node: 8 or 4
    constexpr int NPB = 256 / G;         // nodes per block: 32 or 64
    constexpr int FOUT = ROWU * 2;
    const int gslot = blockIdx.x * NPB + (int)(threadIdx.x / G);
    const int t = threadIdx.x % G;
    if (gslot >= n) return;
    const int4v mi = meta[gslot];
    const int start = mi[0];
    const int deg = mi[1];
    const int node = mi[2];
    union { int i; float f; } dv; dv.i = mi[3];
    const float dd = dv.f;
    const int pend = start + ((deg + 3) & ~3);
    const unsigned* __restrict__ HSt = HS + 4 * t;
    const uint4v own = *(const uint4v*)(HS + (size_t)node * ROWU + 4 * t);
    float2v acc[4];   // acc[k] = {lo, hi} accumulators for uint k of this lane's slice
#pragma unroll
    for (int k = 0; k < 4; ++k) {
        float2v o = bfpair(own[k]);
        acc[k][0] = 2.0f * o[0];
        acc[k][1] = 2.0f * o[1];
    }
    int j = start;
    for (; j + 8 <= pend; j += 8) {
        int4v s0 = __builtin_nontemporal_load((const int4v*)(csrc + j));
        int4v s1 = __builtin_nontemporal_load((const int4v*)(csrc + j + 4));
        uint4v u0 = *(const uint4v*)(HSt + (size_t)s0[0] * ROWU);
        uint4v u1 = *(const uint4v*)(HSt + (size_t)s0[1] * ROWU);
        uint4v u2 = *(const uint4v*)(HSt + (size_t)s0[2] * ROWU);
        uint4v u3 = *(const uint4v*)(HSt + (size_t)s0[3] * ROWU);
        uint4v u4 = *(const uint4v*)(HSt + (size_t)s1[0] * ROWU);
        uint4v u5 = *(const uint4v*)(HSt + (size_t)s1[1] * ROWU);
        uint4v u6 = *(const uint4v*)(HSt + (size_t)s1[2] * ROWU);
        uint4v u7 = *(const uint4v*)(HSt + (size_t)s1[3] * ROWU);
#pragma unroll
        for (int k = 0; k < 4; ++k) {
            float2v p01 = pk_add(bfpair(u0[k]), bfpair(u1[k]));
            float2v p23 = pk_add(bfpair(u2[k]), bfpair(u3[k]));
            float2v p45 = pk_add(bfpair(u4[k]), bfpair(u5[k]));
            float2v p67 = pk_add(bfpair(u6[k]), bfpair(u7[k]));
            acc[k] = pk_add(acc[k], pk_add(pk_add(p01, p23), pk_add(p45, p67)));
        }
    }
    if (j < pend) {  // exactly one group of 4 (padded counts are multiples of 4)
        int4v s0 = __builtin_nontemporal_load((const int4v*)(csrc + j));
        uint4v u0 = *(const uint4v*)(HSt + (size_t)s0[0] * ROWU);
        uint4v u1 = *(const uint4v*)(HSt + (size_t)s0[1] * ROWU);
        uint4v u2 = *(const uint4v*)(HSt + (size_t)s0[2] * ROWU);
        uint4v u3 = *(const uint4v*)(HSt + (size_t)s0[3] * ROWU);
#pragma unroll
        for (int k = 0; k < 4; ++k) {
            float2v p01 = pk_add(bfpair(u0[k]), bfpair(u1[k]));
            float2v p23 = pk_add(bfpair(u2[k]), bfpair(u3[k]));
            acc[k] = pk_add(acc[k], pk_add(p01, p23));
        }
    }
    const int ch = t >> 2;               // 0 when ROWU==16
    const int c0 = (4 * t) & 15;
    const float4v blv = *(const float4v*)(bias + 32 * ch + c0);
    const float4v bhv = *(const float4v*)(bias + 32 * ch + 16 + c0);
    float4v olo, ohi;
#pragma unroll
    for (int k = 0; k < 4; ++k) {
        float o0 = acc[k][0] * dd + blv[k];
        float o1 = acc[k][1] * dd + bhv[k];
        if (RELU) { o0 = fmaxf(o0, 0.0f); o1 = fmaxf(o1, 0.0f); }
        olo[k] = o0;
        ohi[k] = o1;
    }
    float* op = OUT + (size_t)node * FOUT + 32 * ch + c0;
    __builtin_nontemporal_store(olo, (float4v*)op);
    __builtin_nontemporal_store(ohi, (float4v*)(op + 16));
}

extern "C" void kernel_launch(void* const* d_in, const int* in_sizes, int n_in,
                              void* d_out, int out_size, void* d_ws, size_t ws_size,
                              hipStream_t stream) {
    const float* x  = (const float*)d_in[0];   // [N,64]
    const int*   ei = (const int*)d_in[1];     // [2,E] row-major: src then dst
    const float* W1 = (const float*)d_in[2];   // [64,64]
    const float* b1 = (const float*)d_in[3];   // [64]
    const float* W2 = (const float*)d_in[4];   // [64,32]
    const float* b2 = (const float*)d_in[5];   // [32]

    const int* srcp = ei;
    const int* dstp = ei + E_EDGES;

    // tuple return order: (out [N,32], feature_map [N,64]) concatenated flat
    float* out = (float*)d_out;                   // N*32
    float* fm  = (float*)d_out + N_NODES * 32;    // N*64 (also h1 input to layer 2)

    // workspace layout, every array 256B-aligned (HS rows must not straddle 64B lines)
    char* w = (char*)d_ws;
    auto alloc = [&w](size_t bytes) -> void* {
        uintptr_t p = ((uintptr_t)w + 255) & ~(uintptr_t)255;
        w = (char*)(p + bytes);
        return (void*)p;
    };
    int*      gcursor  = (int*)alloc(sizeof(int) * NBUCK);
    int4v*    meta     = (int4v*)alloc(sizeof(int4v) * N_NODES);
    float*    dinv     = (float*)alloc(sizeof(float) * N_NODES);
    int*      csrc     = (int*)alloc(sizeof(int) * (size_t)NBUCK * CSR_STRIDE);  // fixed stride
    unsigned* staged   = (unsigned*)alloc(sizeof(unsigned) * (size_t)NBUCK * BUCKET_CAP);
    unsigned* HS1      = (unsigned*)alloc(sizeof(unsigned) * (size_t)(N_NODES + 1) * 32);
    unsigned* HS2      = (unsigned*)alloc(sizeof(unsigned) * (size_t)(N_NODES + 1) * 16);

    // ---- graph preprocessing (shared by both layers) ----
    cursor_init_kernel<<<(NBUCK + 255) / 256, 256, 0, stream>>>(gcursor, HS1, HS2);
    stage_kernel<<<(E_EDGES + STAGE_CHUNK - 1) / STAGE_CHUNK, STAGE_TPB, 0, stream>>>(
        srcp, dstp, gcursor, staged, E_EDGES);
    bucket_csr_kernel<<<NBUCK, 256, 0, stream>>>(staged, gcursor, meta, dinv, csrc, N_NODES);

    // ---- layer 1: HS1 = bf16((x@W1)*dinv) via MFMA; fm = relu(gather), 128B rows ----
    linear_mfma_kernel<64><<<512, 256, 0, stream>>>(x, W1, dinv, HS1, N_NODES);
    gather_vec_kernel<32, true><<<(N_NODES + 31) / 32, 256, 0, stream>>>(
        meta, csrc, HS1, b1, fm, N_NODES);

    // ---- layer 2: HS2 = bf16((fm@W2)*dinv) via MFMA; out = gather, 64B rows ----
    linear_mfma_kernel<32><<<512, 256, 0, stream>>>(fm, W2, dinv, HS2, N_NODES);
    gather_vec_kernel<16, false><<<(N_NODES + 63) / 64, 256, 0, stream>>>(
        meta, csrc, HS2, b2, out, N_NODES);
}